// Round 8
// baseline (161.058 us; speedup 1.0000x reference)
//
#include <hip/hip_runtime.h>
#include <hip/hip_bf16.h>

#define SL 2048
#define NH 16
#define HD 128
#define EMB 2048

typedef __attribute__((ext_vector_type(8))) __bf16 bf16x8;
typedef __attribute__((ext_vector_type(4))) float f32x4;
typedef __attribute__((ext_vector_type(8))) short short8;

__device__ __forceinline__ short bf16bits(float x) {
  union { __hip_bfloat16 h; short s; } u;
  u.h = __float2bfloat16(x);
  return u.s;
}

#define GLDS16(gp, lp) __builtin_amdgcn_global_load_lds( \
    (__attribute__((address_space(1))) void*)(gp), \
    (__attribute__((address_space(3))) void*)(lp), 16, 0, 0)

// ---------------------------------------------------------------- casts
__global__ __launch_bounds__(256) void cast_f32_bf16(const float* __restrict__ in,
                                                     short* __restrict__ out, int n) {
  int i = (blockIdx.x * 256 + threadIdx.x) * 8;
  if (i >= n) return;
  float4 a = *(const float4*)(in + i);
  float4 b = *(const float4*)(in + i + 4);
  short8 o;
  o[0] = bf16bits(a.x); o[1] = bf16bits(a.y); o[2] = bf16bits(a.z); o[3] = bf16bits(a.w);
  o[4] = bf16bits(b.x); o[5] = bf16bits(b.y); o[6] = bf16bits(b.z); o[7] = bf16bits(b.w);
  *(short8*)(out + i) = o;
}

// --------------------------------- 2-phase dbuf NT GEMM, 64(M)x128(N) tile, 1D grid
// (r7-proven, verbatim)
template<int MODE>
__global__ __launch_bounds__(256, 3) void gemm64(const short* __restrict__ A,
                                                 const short* __restrict__ B,
                                                 float* __restrict__ C,
                                                 short* __restrict__ Qb,
                                                 short* __restrict__ Kb,
                                                 short* __restrict__ VT,
                                                 const float* __restrict__ cosT,
                                                 const float* __restrict__ sinT,
                                                 const float* __restrict__ gamma) {
  __shared__ char lds_raw[24576];
  short* As = (short*)lds_raw;             // [2][64*32]  8 KB
  short* Bs = (short*)(lds_raw + 8192);    // [2][128*32] 16 KB
  const int K = 2048;
  int nwg = gridDim.x;                          // multiple of 8
  int id = blockIdx.x;
  int nid = (id & 7) * (nwg >> 3) + (id >> 3);  // bijective XCD swizzle (nwg%8==0)
  int tn = nid >> 5;                            // consecutive nid share B panel
  int tm = nid & 31;
  int tid = threadIdx.x;
  int wave = tid >> 6, lane = tid & 63;
  int g = lane >> 4, c = lane & 15;
  int wr = wave >> 1, wc = wave & 1;
  const short* Ab = A + (long)(tm * 64) * K;
  const short* Bb = B + (long)(tn * 128) * K;
  f32x4 zero = {0.f, 0.f, 0.f, 0.f};
  f32x4 acc[2][4];
#pragma unroll
  for (int m = 0; m < 2; ++m)
#pragma unroll
    for (int n = 0; n < 4; ++n) acc[m][n] = zero;

#define STG(buf, kt) do { \
    GLDS16(Ab + (long)(wave * 16 + (lane >> 2)) * K + (kt) + (lane & 3) * 8, \
           As + (buf) * 2048 + wave * 512); \
    _Pragma("unroll") \
    for (int hh = 0; hh < 2; ++hh) { \
      int rb = wave * 32 + hh * 16; \
      GLDS16(Bb + (long)(rb + (lane >> 2)) * K + (kt) + (lane & 3) * 8, \
             Bs + (buf) * 4096 + rb * 32); \
    } } while (0)

  STG(0, 0);
  asm volatile("s_waitcnt vmcnt(0)" ::: "memory");
  __builtin_amdgcn_s_barrier();

  for (int it = 0; it < 64; ++it) {
    int cur = it & 1;
    if (it < 63) STG(cur ^ 1, (it + 1) * 32);
    bf16x8 a[2], b[4];
#pragma unroll
    for (int m = 0; m < 2; ++m)
      a[m] = *(const bf16x8*)(As + cur * 2048 + (wr * 32 + m * 16 + c) * 32 + g * 8);
#pragma unroll
    for (int n = 0; n < 4; ++n)
      b[n] = *(const bf16x8*)(Bs + cur * 4096 + (wc * 64 + n * 16 + c) * 32 + g * 8);
    __builtin_amdgcn_s_setprio(1);
#pragma unroll
    for (int m = 0; m < 2; ++m)
#pragma unroll
      for (int n = 0; n < 4; ++n)
        acc[m][n] = __builtin_amdgcn_mfma_f32_16x16x32_bf16(a[m], b[n], acc[m][n], 0, 0, 0);
    __builtin_amdgcn_s_setprio(0);
    if (it < 63) asm volatile("s_waitcnt vmcnt(0)" ::: "memory");
    __builtin_amdgcn_s_barrier();
  }
#undef STG

  if constexpr (MODE == 0) {
#pragma unroll
    for (int m = 0; m < 2; ++m)
#pragma unroll
      for (int n = 0; n < 4; ++n)
#pragma unroll
        for (int r = 0; r < 4; ++r) {
          int row = tm * 64 + wr * 32 + m * 16 + g * 4 + r;
          int col = tn * 128 + wc * 64 + n * 16 + c;
          C[(long)row * 2048 + col] = acc[m][n][r];
        }
  } else {
    if (tn < 16) {
      __shared__ float ssb[2][64];
      float* xch = (float*)lds_raw;   // 17.4 KB <= 24 KB arena (K-loop LDS dead)
      float ssmr[2][4];
#pragma unroll
      for (int m = 0; m < 2; ++m)
#pragma unroll
        for (int r = 0; r < 4; ++r) {
          float s = 0.f;
#pragma unroll
          for (int n = 0; n < 4; ++n) s += acc[m][n][r] * acc[m][n][r];
#pragma unroll
          for (int off = 1; off <= 8; off <<= 1) s += __shfl_xor(s, off, 64);
          ssmr[m][r] = s;
        }
      if (c == 0) {
#pragma unroll
        for (int m = 0; m < 2; ++m)
#pragma unroll
          for (int r = 0; r < 4; ++r)
            ssb[wc][wr * 32 + m * 16 + g * 4 + r] = ssmr[m][r];
      }
      __syncthreads();
      float rn[2][4];
#pragma unroll
      for (int m = 0; m < 2; ++m)
#pragma unroll
        for (int r = 0; r < 4; ++r) {
          int rowloc = wr * 32 + m * 16 + g * 4 + r;
          rn[m][r] = rsqrtf((ssb[0][rowloc] + ssb[1][rowloc]) * (1.0f / 128.0f) + 1e-6f);
        }
      float g_own[4], g_par[4];
#pragma unroll
      for (int n = 0; n < 4; ++n) {
        g_own[n] = gamma[wc * 64 + n * 16 + c];
        g_par[n] = gamma[(wc ^ 1) * 64 + n * 16 + c];
      }
      float sgn = wc ? 1.f : -1.f;
#pragma unroll
      for (int m = 0; m < 2; ++m) {
        __syncthreads();   // waves done with K-loop LDS / previous xch use (WAR)
#pragma unroll
        for (int n = 0; n < 4; ++n)
#pragma unroll
          for (int r = 0; r < 4; ++r)
            xch[tid * 17 + n * 4 + r] = acc[m][n][r];
        __syncthreads();
        float xp[4][4];
#pragma unroll
        for (int n = 0; n < 4; ++n)
#pragma unroll
          for (int r = 0; r < 4; ++r)
            xp[n][r] = xch[(tid ^ 64) * 17 + n * 4 + r];
#pragma unroll
        for (int n = 0; n < 4; ++n)
#pragma unroll
          for (int r = 0; r < 4; ++r) {
            int s = tm * 64 + wr * 32 + m * 16 + g * 4 + r;
            int u = n * 16 + c;                    // cos/sin periodic in 64
            float cv = cosT[s * 128 + u];
            float sv = sinT[s * 128 + u];
            float xo = acc[m][n][r] * rn[m][r] * g_own[n];
            float xq = xp[n][r] * rn[m][r] * g_par[n];
            float y  = xo * cv + sgn * xq * sv;    // rope(Q)
            float yp = xq * cv - sgn * xo * sv;    // rope(Q) at partner d
            float kk = y * cv + sgn * yp * sv;     // rope(rope(Q))  (source bug)
            long o = ((long)tn * SL + s) * HD + wc * 64 + u;
            Qb[o] = bf16bits(y);
            Kb[o] = bf16bits(kk);
          }
      }
    } else {
      // V^T [d][s]
#pragma unroll
      for (int m = 0; m < 2; ++m)
#pragma unroll
        for (int n = 0; n < 4; ++n)
#pragma unroll
          for (int r = 0; r < 4; ++r) {
            int s = tm * 64 + wr * 32 + m * 16 + g * 4 + r;
            int d = wc * 64 + n * 16 + c;
            VT[(long)d * SL + s] = bf16bits(acc[m][n][r]);
          }
    }
  }
}

// ---------------------------------------------------------- causal flash attention
// grid (32,16): block x processes strip qt=x THEN qt=31-x -> every block runs
// exactly 33 uniform slots (full 2-blocks/CU concurrency, no drain tail).
// Swapped QK^T: sf = mfma(K, Q) -> S^T with col=q=c, row=k=g*4+r(+16n). Row-max is
// lane-local (15 fmax) + 2 shfls; exp uses lane-local m; l is a per-lane partial
// (reduced in epilogue); P pairs packed to 8 ds_write_b32. O-rescale redistribution
// (4 bpermutes) only on the rare defer-max trigger (THR=8).
// K/V staging + PV read paths byte-identical to the r6/r7-proven kernel.
__global__ __launch_bounds__(256, 2) void attn(const short* __restrict__ Qb,
                                               const short* __restrict__ Kb,
                                               const short* __restrict__ VTg,
                                               short* __restrict__ att) {
  __shared__ short Ks[2][64 * 128];   // 32 KB
  __shared__ short Vs[2][128 * 64];   // 32 KB  V^T tile [d][k-chunk swizzled]
  __shared__ short Ps[4][16 * 72];    // 9 KB per-wave
  int wave = threadIdx.x >> 6, lane = threadIdx.x & 63;
  int g = lane >> 4, c = lane & 15;
  int h = blockIdx.y;
  int x = blockIdx.x;                 // strip-pair index
  const short* Qh = Qb + (long)h * SL * HD;
  const short* Kh = Kb + (long)h * SL * HD;
  f32x4 zero = {0.f, 0.f, 0.f, 0.f};
  const float sc = 0.08838834764831845f;   // 1/sqrt(128)

#define ASTAGE(b, kvb) do { \
    _Pragma("unroll") \
    for (int i = 0; i < 4; ++i) { \
      int rb = wave * 16 + i * 4; \
      int row = rb + (lane >> 4); \
      int c16 = (lane & 15) ^ (row & 7); \
      GLDS16(Kh + (long)((kvb) + row) * HD + c16 * 8, &Ks[b][rb * 128]); \
    } \
    _Pragma("unroll") \
    for (int i = 0; i < 4; ++i) { \
      int dbase = i * 32 + wave * 8; \
      int drow = dbase + (lane >> 3); \
      int u8 = (lane & 7) ^ (drow & 7); \
      GLDS16(VTg + (long)drow * SL + (kvb) + u8 * 8, &Vs[b][dbase * 64]); \
    } } while (0)

  ASTAGE(0, 0);
  int s = 0;                           // global slot counter 0..32

  for (int phase = 0; phase < 2; ++phase) {
    int qt = phase ? (31 - x) : x;
    int nt = qt + 1;
    int qb = qt * 64 + wave * 16;
    int qown = qb + c;                 // this lane's q row

    bf16x8 aq[4];
#pragma unroll
    for (int kc = 0; kc < 4; ++kc)
      aq[kc] = *(const bf16x8*)(Qh + (long)qown * HD + kc * 32 + g * 8);

    float m = -1e30f, l = 0.f;
    f32x4 O[8];
#pragma unroll
    for (int d8 = 0; d8 < 8; ++d8) O[d8] = zero;

    for (int kt = 0; kt < nt; ++kt, ++s) {
      int kvb = kt * 64;
      int bcu = s & 1;
      asm volatile("s_waitcnt vmcnt(0)" ::: "memory");
      __builtin_amdgcn_s_barrier();
      {
        int ns = s + 1;
        if (ns < 33) {
          int kvn = (ns <= x) ? ns * 64 : (ns - x - 1) * 64;
          ASTAGE(bcu ^ 1, kvn);
        }
      }

      // S^T = K Q^T   (A = K rows from LDS, B = Q from regs)
      f32x4 sf[4];
#pragma unroll
      for (int n = 0; n < 4; ++n) sf[n] = zero;
      __builtin_amdgcn_s_setprio(1);
#pragma unroll
      for (int kc = 0; kc < 4; ++kc)
#pragma unroll
        for (int n = 0; n < 4; ++n) {
          int row = n * 16 + c;
          int u = (kc * 4 + g) ^ (row & 7);
          bf16x8 bk = *(const bf16x8*)(&Ks[bcu][row * 128 + u * 8]);
          sf[n] = __builtin_amdgcn_mfma_f32_16x16x32_bf16(bk, aq[kc], sf[n], 0, 0, 0);
        }
      __builtin_amdgcn_s_setprio(0);

      // mask + scale; per-lane row max (all 16 values share q = qown)
      float pm = -1e30f;
#pragma unroll
      for (int n = 0; n < 4; ++n) {
#pragma unroll
        for (int r = 0; r < 4; ++r) {
          int k = kvb + n * 16 + g * 4 + r;
          float v = sf[n][r] * sc;
          if (k > qown) v = -1e30f;
          sf[n][r] = v;
        }
        float a0 = fmaxf(sf[n][0], sf[n][1]);
        float a1 = fmaxf(sf[n][2], sf[n][3]);
        pm = fmaxf(pm, fmaxf(a0, a1));
      }
      pm = fmaxf(pm, __shfl_xor(pm, 16, 64));
      pm = fmaxf(pm, __shfl_xor(pm, 32, 64));

      // defer-max (T13)
      if (__any(pm > m + 8.f)) {
        float mn_ = fmaxf(m, pm);
        float corr = __expf(m - mn_);
        m = mn_;
        l *= corr;
        float c4[4];
#pragma unroll
        for (int r = 0; r < 4; ++r) c4[r] = __shfl(corr, g * 4 + r, 64);
#pragma unroll
        for (int d8 = 0; d8 < 8; ++d8)
#pragma unroll
          for (int r = 0; r < 4; ++r) O[d8][r] *= c4[r];
      }

      // exp, pack pairs, store Ps (8 x b32), accumulate lane-partial l
#pragma unroll
      for (int n = 0; n < 4; ++n)
#pragma unroll
        for (int hh = 0; hh < 2; ++hh) {
          float p0 = __expf(sf[n][2 * hh + 0] - m);
          float p1 = __expf(sf[n][2 * hh + 1] - m);
          l += p0 + p1;
          unsigned pk = (unsigned)(unsigned short)bf16bits(p0) |
                        ((unsigned)(unsigned short)bf16bits(p1) << 16);
          *(unsigned*)&Ps[wave][c * 72 + n * 16 + g * 4 + 2 * hh] = pk;
        }

      // O += P V  (A-frags from Ps rows q=c; B-frags from Vs, proven path)
#pragma unroll
      for (int k2 = 0; k2 < 2; ++k2) {
        bf16x8 ap = *(const bf16x8*)(&Ps[wave][c * 72 + k2 * 32 + g * 8]);
        __builtin_amdgcn_s_setprio(1);
#pragma unroll
        for (int d8 = 0; d8 < 8; ++d8) {
          int drow = d8 * 16 + c;
          int u = (k2 * 4 + g) ^ (c & 7);
          bf16x8 bv = *(const bf16x8*)(&Vs[bcu][drow * 64 + u * 8]);
          O[d8] = __builtin_amdgcn_mfma_f32_16x16x32_bf16(ap, bv, O[d8], 0, 0, 0);
        }
        __builtin_amdgcn_s_setprio(0);
      }
    }

    // phase epilogue: reduce l across g-lanes, redistribute to O rows, store
    float lf = l;
    lf += __shfl_xor(lf, 16, 64);
    lf += __shfl_xor(lf, 32, 64);
    float rinv = 1.0f / lf;
    float r4[4];
#pragma unroll
    for (int r = 0; r < 4; ++r) r4[r] = __shfl(rinv, g * 4 + r, 64);
#pragma unroll
    for (int d8 = 0; d8 < 8; ++d8)
#pragma unroll
      for (int r = 0; r < 4; ++r) {
        int q = qb + g * 4 + r;
        att[(long)q * EMB + h * HD + d8 * 16 + c] = bf16bits(O[d8][r] * r4[r]);
      }
  }
#undef ASTAGE
}

// ---------------------------------------------------------------------- launch
extern "C" void kernel_launch(void* const* d_in, const int* in_sizes, int n_in,
                              void* d_out, int out_size, void* d_ws, size_t ws_size,
                              hipStream_t stream) {
  const float* x    = (const float*)d_in[0];
  const float* cosT = (const float*)d_in[1];
  const float* sinT = (const float*)d_in[2];
  const float* Wq   = (const float*)d_in[3];
  const float* Wv   = (const float*)d_in[5];
  const float* Wo   = (const float*)d_in[6];
  const float* qg   = (const float*)d_in[7];

  char* w = (char*)d_ws;
  short* xb   = (short*)(w + 0);          //  8.0 MB  x bf16 [2048][2048]
  short* wqvb = (short*)(w + 8388608);    //  8.5 MB  [Wq;Wv] bf16 [2176][2048]
  short* wob  = (short*)(w + 17301504);   //  8.0 MB  Wo bf16
  short* vt   = (short*)(w + 25690112);   //  0.5 MB  V^T bf16 [128][2048]
  short* qb   = (short*)(w + 26214400);   //  8.0 MB  Q roped bf16 [16][2048][128]
  short* kb   = (short*)(w + 34603008);   //  8.0 MB  K roped bf16 [16][2048][128]
  short* attb = (short*)(w + 42991616);   //  8.0 MB  att bf16 [2048][2048]

  cast_f32_bf16<<<dim3(2048), dim3(256), 0, stream>>>(x,  xb,   4194304);
  cast_f32_bf16<<<dim3(2048), dim3(256), 0, stream>>>(Wq, wqvb, 4194304);
  cast_f32_bf16<<<dim3(128),  dim3(256), 0, stream>>>(Wv, wqvb + 4194304, 262144);
  cast_f32_bf16<<<dim3(2048), dim3(256), 0, stream>>>(Wo, wob,  4194304);

  gemm64<1><<<dim3(544), dim3(256), 0, stream>>>(xb, wqvb, nullptr, qb, kb, vt,
                                                 cosT, sinT, qg);
  attn<<<dim3(32, 16), dim3(256), 0, stream>>>(qb, kb, vt, attb);
  gemm64<0><<<dim3(512), dim3(256), 0, stream>>>(attb, wob, (float*)d_out,
                                                 nullptr, nullptr, nullptr,
                                                 nullptr, nullptr, nullptr);
}

// Round 9
// 138.356 us; speedup vs baseline: 1.1641x; 1.1641x over previous
//
#include <hip/hip_runtime.h>
#include <hip/hip_bf16.h>

#define SL 2048
#define NH 16
#define HD 128
#define EMB 2048

typedef __attribute__((ext_vector_type(8))) __bf16 bf16x8;
typedef __attribute__((ext_vector_type(4))) float f32x4;
typedef __attribute__((ext_vector_type(8))) short short8;

__device__ __forceinline__ short bf16bits(float x) {
  union { __hip_bfloat16 h; short s; } u;
  u.h = __float2bfloat16(x);
  return u.s;
}

#define GLDS16(gp, lp) __builtin_amdgcn_global_load_lds( \
    (__attribute__((address_space(1))) void*)(gp), \
    (__attribute__((address_space(3))) void*)(lp), 16, 0, 0)

// ---------------------------------------------------------------- casts
__global__ __launch_bounds__(256) void cast_f32_bf16(const float* __restrict__ in,
                                                     short* __restrict__ out, int n) {
  int i = (blockIdx.x * 256 + threadIdx.x) * 8;
  if (i >= n) return;
  float4 a = *(const float4*)(in + i);
  float4 b = *(const float4*)(in + i + 4);
  short8 o;
  o[0] = bf16bits(a.x); o[1] = bf16bits(a.y); o[2] = bf16bits(a.z); o[3] = bf16bits(a.w);
  o[4] = bf16bits(b.x); o[5] = bf16bits(b.y); o[6] = bf16bits(b.z); o[7] = bf16bits(b.w);
  *(short8*)(out + i) = o;
}

// --------------------------------- 2-phase dbuf NT GEMM, 64(M)x128(N) tile, 1D grid
// (r7-proven, verbatim)
template<int MODE>
__global__ __launch_bounds__(256, 3) void gemm64(const short* __restrict__ A,
                                                 const short* __restrict__ B,
                                                 float* __restrict__ C,
                                                 short* __restrict__ Qb,
                                                 short* __restrict__ Kb,
                                                 short* __restrict__ VT,
                                                 const float* __restrict__ cosT,
                                                 const float* __restrict__ sinT,
                                                 const float* __restrict__ gamma) {
  __shared__ char lds_raw[24576];
  short* As = (short*)lds_raw;             // [2][64*32]  8 KB
  short* Bs = (short*)(lds_raw + 8192);    // [2][128*32] 16 KB
  const int K = 2048;
  int nwg = gridDim.x;                          // multiple of 8
  int id = blockIdx.x;
  int nid = (id & 7) * (nwg >> 3) + (id >> 3);  // bijective XCD swizzle (nwg%8==0)
  int tn = nid >> 5;                            // consecutive nid share B panel
  int tm = nid & 31;
  int tid = threadIdx.x;
  int wave = tid >> 6, lane = tid & 63;
  int g = lane >> 4, c = lane & 15;
  int wr = wave >> 1, wc = wave & 1;
  const short* Ab = A + (long)(tm * 64) * K;
  const short* Bb = B + (long)(tn * 128) * K;
  f32x4 zero = {0.f, 0.f, 0.f, 0.f};
  f32x4 acc[2][4];
#pragma unroll
  for (int m = 0; m < 2; ++m)
#pragma unroll
    for (int n = 0; n < 4; ++n) acc[m][n] = zero;

#define STG(buf, kt) do { \
    GLDS16(Ab + (long)(wave * 16 + (lane >> 2)) * K + (kt) + (lane & 3) * 8, \
           As + (buf) * 2048 + wave * 512); \
    _Pragma("unroll") \
    for (int hh = 0; hh < 2; ++hh) { \
      int rb = wave * 32 + hh * 16; \
      GLDS16(Bb + (long)(rb + (lane >> 2)) * K + (kt) + (lane & 3) * 8, \
             Bs + (buf) * 4096 + rb * 32); \
    } } while (0)

  STG(0, 0);
  asm volatile("s_waitcnt vmcnt(0)" ::: "memory");
  __builtin_amdgcn_s_barrier();

  for (int it = 0; it < 64; ++it) {
    int cur = it & 1;
    if (it < 63) STG(cur ^ 1, (it + 1) * 32);
    bf16x8 a[2], b[4];
#pragma unroll
    for (int m = 0; m < 2; ++m)
      a[m] = *(const bf16x8*)(As + cur * 2048 + (wr * 32 + m * 16 + c) * 32 + g * 8);
#pragma unroll
    for (int n = 0; n < 4; ++n)
      b[n] = *(const bf16x8*)(Bs + cur * 4096 + (wc * 64 + n * 16 + c) * 32 + g * 8);
    __builtin_amdgcn_s_setprio(1);
#pragma unroll
    for (int m = 0; m < 2; ++m)
#pragma unroll
      for (int n = 0; n < 4; ++n)
        acc[m][n] = __builtin_amdgcn_mfma_f32_16x16x32_bf16(a[m], b[n], acc[m][n], 0, 0, 0);
    __builtin_amdgcn_s_setprio(0);
    if (it < 63) asm volatile("s_waitcnt vmcnt(0)" ::: "memory");
    __builtin_amdgcn_s_barrier();
  }
#undef STG

  if constexpr (MODE == 0) {
#pragma unroll
    for (int m = 0; m < 2; ++m)
#pragma unroll
      for (int n = 0; n < 4; ++n)
#pragma unroll
        for (int r = 0; r < 4; ++r) {
          int row = tm * 64 + wr * 32 + m * 16 + g * 4 + r;
          int col = tn * 128 + wc * 64 + n * 16 + c;
          C[(long)row * 2048 + col] = acc[m][n][r];
        }
  } else {
    if (tn < 16) {
      __shared__ float ssb[2][64];
      float* xch = (float*)lds_raw;   // 17.4 KB <= 24 KB arena (K-loop LDS dead)
      float ssmr[2][4];
#pragma unroll
      for (int m = 0; m < 2; ++m)
#pragma unroll
        for (int r = 0; r < 4; ++r) {
          float s = 0.f;
#pragma unroll
          for (int n = 0; n < 4; ++n) s += acc[m][n][r] * acc[m][n][r];
#pragma unroll
          for (int off = 1; off <= 8; off <<= 1) s += __shfl_xor(s, off, 64);
          ssmr[m][r] = s;
        }
      if (c == 0) {
#pragma unroll
        for (int m = 0; m < 2; ++m)
#pragma unroll
          for (int r = 0; r < 4; ++r)
            ssb[wc][wr * 32 + m * 16 + g * 4 + r] = ssmr[m][r];
      }
      __syncthreads();
      float rn[2][4];
#pragma unroll
      for (int m = 0; m < 2; ++m)
#pragma unroll
        for (int r = 0; r < 4; ++r) {
          int rowloc = wr * 32 + m * 16 + g * 4 + r;
          rn[m][r] = rsqrtf((ssb[0][rowloc] + ssb[1][rowloc]) * (1.0f / 128.0f) + 1e-6f);
        }
      float g_own[4], g_par[4];
#pragma unroll
      for (int n = 0; n < 4; ++n) {
        g_own[n] = gamma[wc * 64 + n * 16 + c];
        g_par[n] = gamma[(wc ^ 1) * 64 + n * 16 + c];
      }
      float sgn = wc ? 1.f : -1.f;
#pragma unroll
      for (int m = 0; m < 2; ++m) {
        __syncthreads();   // waves done with K-loop LDS / previous xch use (WAR)
#pragma unroll
        for (int n = 0; n < 4; ++n)
#pragma unroll
          for (int r = 0; r < 4; ++r)
            xch[tid * 17 + n * 4 + r] = acc[m][n][r];
        __syncthreads();
        float xp[4][4];
#pragma unroll
        for (int n = 0; n < 4; ++n)
#pragma unroll
          for (int r = 0; r < 4; ++r)
            xp[n][r] = xch[(tid ^ 64) * 17 + n * 4 + r];
#pragma unroll
        for (int n = 0; n < 4; ++n)
#pragma unroll
          for (int r = 0; r < 4; ++r) {
            int s = tm * 64 + wr * 32 + m * 16 + g * 4 + r;
            int u = n * 16 + c;                    // cos/sin periodic in 64
            float cv = cosT[s * 128 + u];
            float sv = sinT[s * 128 + u];
            float xo = acc[m][n][r] * rn[m][r] * g_own[n];
            float xq = xp[n][r] * rn[m][r] * g_par[n];
            float y  = xo * cv + sgn * xq * sv;    // rope(Q)
            float yp = xq * cv - sgn * xo * sv;    // rope(Q) at partner d
            float kk = y * cv + sgn * yp * sv;     // rope(rope(Q))  (source bug)
            long o = ((long)tn * SL + s) * HD + wc * 64 + u;
            Qb[o] = bf16bits(y);
            Kb[o] = bf16bits(kk);
          }
      }
    } else {
      // V^T [d][s]
#pragma unroll
      for (int m = 0; m < 2; ++m)
#pragma unroll
        for (int n = 0; n < 4; ++n)
#pragma unroll
          for (int r = 0; r < 4; ++r) {
            int s = tm * 64 + wr * 32 + m * 16 + g * 4 + r;
            int d = wc * 64 + n * 16 + c;
            VT[(long)d * SL + s] = bf16bits(acc[m][n][r]);
          }
    }
  }
}

// ------------------------------------------- causal flash attention, k-split chunks
// grid (32,16): x = blockIdx.x&15 (strip pair), chunk = blockIdx.x>>4.
// chunk A (17 slots): all of short strip qt=x  -> DIRECT att write;
//                     k-tiles 0..15-x of long strip qt=31-x -> partial 0.
// chunk B (16 slots): k-tiles 16-x..31-x of long strip -> partial 1.
// 512 uniform blocks = 2/CU, no duplication. Partials (unnorm O f32, m, l) in ws;
// attn_comb merges. Mask only applied on the diagonal tile (kt==qt).
// Inner loop (staging/QK/softmax/PV) identical to the r8-proven kernel.
__global__ __launch_bounds__(256, 2) void attn_part(const short* __restrict__ Qb,
                                                    const short* __restrict__ Kb,
                                                    const short* __restrict__ VTg,
                                                    short* __restrict__ att,
                                                    float* __restrict__ pO,
                                                    float* __restrict__ pml) {
  __shared__ short Ks[2][64 * 128];   // 32 KB
  __shared__ short Vs[2][128 * 64];   // 32 KB  V^T tile [d][k-chunk swizzled]
  __shared__ short Ps[4][16 * 72];    // 9 KB per-wave
  int wave = threadIdx.x >> 6, lane = threadIdx.x & 63;
  int g = lane >> 4, c = lane & 15;
  int h = blockIdx.y;
  int x = blockIdx.x & 15;
  int cbk = blockIdx.x >> 4;
  const short* Qh = Qb + (long)h * SL * HD;
  const short* Kh = Kb + (long)h * SL * HD;
  f32x4 zero = {0.f, 0.f, 0.f, 0.f};
  const float sc = 0.08838834764831845f;   // 1/sqrt(128)

  int pqt[2], plo[2], pcnt[2], pout[2];    // pout: 0=direct, 1=partial0, 2=partial1
  if (cbk == 0) {
    pqt[0] = x;      plo[0] = 0;      pcnt[0] = x + 1;  pout[0] = 0;
    pqt[1] = 31 - x; plo[1] = 0;      pcnt[1] = 16 - x; pout[1] = 1;
  } else {
    pqt[0] = 31 - x; plo[0] = 16 - x; pcnt[0] = 16;     pout[0] = 2;
    pqt[1] = 0;      plo[1] = 0;      pcnt[1] = 0;      pout[1] = 0;
  }
  int total = pcnt[0] + pcnt[1];

#define ASTAGE(b, kvb) do { \
    _Pragma("unroll") \
    for (int i = 0; i < 4; ++i) { \
      int rb = wave * 16 + i * 4; \
      int row = rb + (lane >> 4); \
      int c16 = (lane & 15) ^ (row & 7); \
      GLDS16(Kh + (long)((kvb) + row) * HD + c16 * 8, &Ks[b][rb * 128]); \
    } \
    _Pragma("unroll") \
    for (int i = 0; i < 4; ++i) { \
      int dbase = i * 32 + wave * 8; \
      int drow = dbase + (lane >> 3); \
      int u8 = (lane & 7) ^ (drow & 7); \
      GLDS16(VTg + (long)drow * SL + (kvb) + u8 * 8, &Vs[b][dbase * 64]); \
    } } while (0)

  ASTAGE(0, plo[0] * 64);
  int s = 0;                           // slot counter within chunk

  for (int p = 0; p < 2; ++p) {
    int nt = pcnt[p];
    if (nt == 0) break;
    int qt = pqt[p];
    int qb = qt * 64 + wave * 16;
    int qown = qb + c;                 // this lane's q row

    bf16x8 aq[4];
#pragma unroll
    for (int kc = 0; kc < 4; ++kc)
      aq[kc] = *(const bf16x8*)(Qh + (long)qown * HD + kc * 32 + g * 8);

    float m = -1e30f, l = 0.f;
    f32x4 O[8];
#pragma unroll
    for (int d8 = 0; d8 < 8; ++d8) O[d8] = zero;

    for (int i = 0; i < nt; ++i, ++s) {
      int kt = plo[p] + i;
      int kvb = kt * 64;
      int bcu = s & 1;
      asm volatile("s_waitcnt vmcnt(0)" ::: "memory");
      __builtin_amdgcn_s_barrier();
      {
        int ns = s + 1;
        if (ns < total) {
          int np = (ns < pcnt[0]) ? 0 : 1;
          int nkt = plo[np] + (ns - (np ? pcnt[0] : 0));
          ASTAGE(bcu ^ 1, nkt * 64);
        }
      }

      // S^T = K Q^T   (A = K rows from LDS, B = Q from regs)
      f32x4 sf[4];
#pragma unroll
      for (int n = 0; n < 4; ++n) sf[n] = zero;
      __builtin_amdgcn_s_setprio(1);
#pragma unroll
      for (int kc = 0; kc < 4; ++kc)
#pragma unroll
        for (int n = 0; n < 4; ++n) {
          int row = n * 16 + c;
          int u = (kc * 4 + g) ^ (row & 7);
          bf16x8 bk = *(const bf16x8*)(&Ks[bcu][row * 128 + u * 8]);
          sf[n] = __builtin_amdgcn_mfma_f32_16x16x32_bf16(bk, aq[kc], sf[n], 0, 0, 0);
        }
      __builtin_amdgcn_s_setprio(0);

      // scale (+mask only on the diagonal tile); per-lane row max
      float pm = -1e30f;
      if (kt == qt) {
#pragma unroll
        for (int n = 0; n < 4; ++n) {
#pragma unroll
          for (int r = 0; r < 4; ++r) {
            int k = kvb + n * 16 + g * 4 + r;
            float v = sf[n][r] * sc;
            if (k > qown) v = -1e30f;
            sf[n][r] = v;
          }
          float a0 = fmaxf(sf[n][0], sf[n][1]);
          float a1 = fmaxf(sf[n][2], sf[n][3]);
          pm = fmaxf(pm, fmaxf(a0, a1));
        }
      } else {
#pragma unroll
        for (int n = 0; n < 4; ++n) {
#pragma unroll
          for (int r = 0; r < 4; ++r) sf[n][r] *= sc;
          float a0 = fmaxf(sf[n][0], sf[n][1]);
          float a1 = fmaxf(sf[n][2], sf[n][3]);
          pm = fmaxf(pm, fmaxf(a0, a1));
        }
      }
      pm = fmaxf(pm, __shfl_xor(pm, 16, 64));
      pm = fmaxf(pm, __shfl_xor(pm, 32, 64));

      // defer-max (T13)
      if (__any(pm > m + 8.f)) {
        float mn_ = fmaxf(m, pm);
        float corr = __expf(m - mn_);
        m = mn_;
        l *= corr;
        float c4[4];
#pragma unroll
        for (int r = 0; r < 4; ++r) c4[r] = __shfl(corr, g * 4 + r, 64);
#pragma unroll
        for (int d8 = 0; d8 < 8; ++d8)
#pragma unroll
          for (int r = 0; r < 4; ++r) O[d8][r] *= c4[r];
      }

      // exp, pack pairs, store Ps (8 x b32), accumulate lane-partial l
#pragma unroll
      for (int n = 0; n < 4; ++n)
#pragma unroll
        for (int hh = 0; hh < 2; ++hh) {
          float p0 = __expf(sf[n][2 * hh + 0] - m);
          float p1 = __expf(sf[n][2 * hh + 1] - m);
          l += p0 + p1;
          unsigned pk = (unsigned)(unsigned short)bf16bits(p0) |
                        ((unsigned)(unsigned short)bf16bits(p1) << 16);
          *(unsigned*)&Ps[wave][c * 72 + n * 16 + g * 4 + 2 * hh] = pk;
        }

      // O += P V
#pragma unroll
      for (int k2 = 0; k2 < 2; ++k2) {
        bf16x8 ap = *(const bf16x8*)(&Ps[wave][c * 72 + k2 * 32 + g * 8]);
        __builtin_amdgcn_s_setprio(1);
#pragma unroll
        for (int d8 = 0; d8 < 8; ++d8) {
          int drow = d8 * 16 + c;
          int u = (k2 * 4 + g) ^ (c & 7);
          bf16x8 bv = *(const bf16x8*)(&Vs[bcu][drow * 64 + u * 8]);
          O[d8] = __builtin_amdgcn_mfma_f32_16x16x32_bf16(ap, bv, O[d8], 0, 0, 0);
        }
        __builtin_amdgcn_s_setprio(0);
      }
    }

    if (pout[p] == 0) {
      // direct epilogue (short strip): normalize and store
      float lf = l;
      lf += __shfl_xor(lf, 16, 64);
      lf += __shfl_xor(lf, 32, 64);
      float rinv = 1.0f / lf;
      float r4[4];
#pragma unroll
      for (int r = 0; r < 4; ++r) r4[r] = __shfl(rinv, g * 4 + r, 64);
#pragma unroll
      for (int d8 = 0; d8 < 8; ++d8)
#pragma unroll
        for (int r = 0; r < 4; ++r) {
          int q = qb + g * 4 + r;
          att[(long)q * EMB + h * HD + d8 * 16 + c] = bf16bits(O[d8][r] * r4[r]);
        }
    } else {
      // partial epilogue: unnormalized O (f32) + per-q m, l
      int part = pout[p] - 1;
      float lf = l;
      lf += __shfl_xor(lf, 16, 64);
      lf += __shfl_xor(lf, 32, 64);
      float* Op = pO + ((long)(part * 16 + x) * 16 + h) * 8192;  // [64][128] f32
#pragma unroll
      for (int d8 = 0; d8 < 8; ++d8)
#pragma unroll
        for (int r = 0; r < 4; ++r)
          Op[(wave * 16 + g * 4 + r) * 128 + d8 * 16 + c] = O[d8][r];
      if (g == 0) {
        float* pmb = pml + ((part * 16 + x) * 16 + h) * 64 + wave * 16 + c;
        pmb[0]     = m;    // q = qb + c
        pmb[32768] = lf;   // l at +2*16*16*64 floats
      }
    }
  }
#undef ASTAGE
}

// ------------------------------------------- combine the two partials (long strips)
__global__ __launch_bounds__(256) void attn_comb(const float* __restrict__ pO,
                                                 const float* __restrict__ pml,
                                                 short* __restrict__ att) {
  int b = blockIdx.x;           // 0..255 = (x, h)
  int x = b & 15, h = b >> 4;
  int qt = 31 - x;
  int t = threadIdx.x;
  int q = t >> 2, d0 = (t & 3) * 32;
  int i0 = (x * 16 + h) * 64 + q;          // part 0
  int i1 = (256 + x * 16 + h) * 64 + q;    // part 1
  float m0 = pml[i0], m1 = pml[i1];
  float l0 = pml[32768 + i0], l1 = pml[32768 + i1];
  float M = fmaxf(m0, m1);
  float w0 = __expf(m0 - M), w1 = __expf(m1 - M);
  float inv = 1.0f / (l0 * w0 + l1 * w1);
  const float* O0 = pO + ((long)(x * 16 + h)) * 8192 + q * 128 + d0;
  const float* O1 = pO + ((long)(256 + x * 16 + h)) * 8192 + q * 128 + d0;
  short* out = att + (long)(qt * 64 + q) * EMB + h * HD + d0;
#pragma unroll
  for (int j = 0; j < 32; j += 4) {
    float4 a = *(const float4*)(O0 + j);
    float4 bb = *(const float4*)(O1 + j);
    out[j + 0] = bf16bits((a.x * w0 + bb.x * w1) * inv);
    out[j + 1] = bf16bits((a.y * w0 + bb.y * w1) * inv);
    out[j + 2] = bf16bits((a.z * w0 + bb.z * w1) * inv);
    out[j + 3] = bf16bits((a.w * w0 + bb.w * w1) * inv);
  }
}

// ---------------------------------------------------------------------- launch
extern "C" void kernel_launch(void* const* d_in, const int* in_sizes, int n_in,
                              void* d_out, int out_size, void* d_ws, size_t ws_size,
                              hipStream_t stream) {
  const float* x    = (const float*)d_in[0];
  const float* cosT = (const float*)d_in[1];
  const float* sinT = (const float*)d_in[2];
  const float* Wq   = (const float*)d_in[3];
  const float* Wv   = (const float*)d_in[5];
  const float* Wo   = (const float*)d_in[6];
  const float* qg   = (const float*)d_in[7];

  char* w = (char*)d_ws;
  short* xb   = (short*)(w + 0);          //  8.0 MB  x bf16 [2048][2048]
  short* wqvb = (short*)(w + 8388608);    //  8.5 MB  [Wq;Wv] bf16 [2176][2048]
  short* wob  = (short*)(w + 17301504);   //  8.0 MB  Wo bf16
  short* vt   = (short*)(w + 25690112);   //  0.5 MB  V^T bf16 [128][2048]
  short* qb   = (short*)(w + 26214400);   //  8.0 MB  Q roped bf16 [16][2048][128]
  short* kb   = (short*)(w + 34603008);   //  8.0 MB  K roped bf16 [16][2048][128]
  short* attb = (short*)(w + 42991616);   //  8.0 MB  att bf16 [2048][2048]
  // partials overlay xb/wqvb (dead after gemm64<1>):
  float* pO   = (float*)(w + 0);          // 16.78 MB [2part][16x][16h][64][128] f32
  float* pml  = (float*)(w + 16777216);   // 512 KB   m then l, [2][16][16][64] each

  cast_f32_bf16<<<dim3(2048), dim3(256), 0, stream>>>(x,  xb,   4194304);
  cast_f32_bf16<<<dim3(2048), dim3(256), 0, stream>>>(Wq, wqvb, 4194304);
  cast_f32_bf16<<<dim3(128),  dim3(256), 0, stream>>>(Wv, wqvb + 4194304, 262144);
  cast_f32_bf16<<<dim3(2048), dim3(256), 0, stream>>>(Wo, wob,  4194304);

  gemm64<1><<<dim3(544), dim3(256), 0, stream>>>(xb, wqvb, nullptr, qb, kb, vt,
                                                 cosT, sinT, qg);
  attn_part<<<dim3(32, 16), dim3(256), 0, stream>>>(qb, kb, vt, attb, pO, pml);
  attn_comb<<<dim3(256), dim3(256), 0, stream>>>(pO, pml, attb);
  gemm64<0><<<dim3(512), dim3(256), 0, stream>>>(attb, wob, (float*)d_out,
                                                 nullptr, nullptr, nullptr,
                                                 nullptr, nullptr, nullptr);
}